// Round 10
// baseline (106.817 us; speedup 1.0000x reference)
//
#include <hip/hip_runtime.h>
#include <hip/hip_bf16.h>

// Problem constants (fixed by reference): B=4, C=64, H=W=64, N=4096
#define BATCH 4
#define NSP   4096

// sqrt(log2(e))/64 — both Q and K carry this, so q·k arrives scaled by
// log2(e)/4096 and softmax numerator is a bare exp2.
#define QKSCALE 0.01876754f

typedef __bf16 bf16x8v __attribute__((ext_vector_type(8)));
typedef __bf16 bf16x4v __attribute__((ext_vector_type(4)));
typedef float  floatx4 __attribute__((ext_vector_type(4)));
typedef short  shortx4 __attribute__((ext_vector_type(4)));

// K=16 bf16 MFMA for direct D->B operand feeding (PV without LDS roundtrip).
// __has_builtin only on the DEVICE pass (host pass probes false — R7); host
// stub must still be __device__ for host-pass semantic checks (R8).
#if defined(__HIP_DEVICE_COMPILE__)
#  if __has_builtin(__builtin_amdgcn_mfma_f32_16x16x16bf16_1k)
static __device__ inline floatx4 mfma16(bf16x4v a, bf16x4v b, floatx4 c) {
    return __builtin_amdgcn_mfma_f32_16x16x16bf16_1k(
        __builtin_bit_cast(shortx4, a), __builtin_bit_cast(shortx4, b), c, 0, 0, 0);
}
#  elif __has_builtin(__builtin_amdgcn_mfma_f32_16x16x16_bf16)
static __device__ inline floatx4 mfma16(bf16x4v a, bf16x4v b, floatx4 c) {
    return __builtin_amdgcn_mfma_f32_16x16x16_bf16(a, b, c, 0, 0, 0);
}
#  else
#    error "gfx950 device pass should have a K=16 bf16 mfma builtin"
#  endif
#else
static __device__ inline floatx4 mfma16(bf16x4v, bf16x4v, floatx4 c) { return c; }
#endif

// ---------------------------------------------------------------------------
// Kernel 1: qkT[b][n][o] = bf16( (sum_c W[o][c]*x[b][c][n] + bias[o])*QKSCALE )
//           xb[b][c][n]  = bf16( x[b][c][n] )   (V source for attn, no cvt there)
// ---------------------------------------------------------------------------
__global__ __launch_bounds__(256) void qk_kernel(const float* __restrict__ x,
                                                 const float* __restrict__ Wm,
                                                 const float* __restrict__ bias,
                                                 __bf16* __restrict__ qkT,
                                                 __bf16* __restrict__ xb) {
    __shared__ __align__(16) __bf16 xT[64 * 72];   // [n][c]; reused as [n][o] out buf

    const int t  = threadIdx.x;
    const int b  = blockIdx.x >> 6;
    const int n0 = (blockIdx.x & 63) << 6;

#pragma unroll
    for (int p = 0; p < 4; ++p) {
        const int c  = p * 16 + (t >> 4);
        const int n4 = (t & 15) * 4;
        const float4 v = *(const float4*)(x + (size_t)(b * 64 + c) * 4096 + n0 + n4);
        xT[(n4 + 0) * 72 + c] = (__bf16)(v.x * QKSCALE);
        xT[(n4 + 1) * 72 + c] = (__bf16)(v.y * QKSCALE);
        xT[(n4 + 2) * 72 + c] = (__bf16)(v.z * QKSCALE);
        xT[(n4 + 3) * 72 + c] = (__bf16)(v.w * QKSCALE);
        bf16x4v xu;
        xu[0] = (__bf16)v.x; xu[1] = (__bf16)v.y; xu[2] = (__bf16)v.z; xu[3] = (__bf16)v.w;
        *(bf16x4v*)(xb + (size_t)(b * 64 + c) * 4096 + n0 + n4) = xu;
    }
    __syncthreads();

    const int w = t >> 6, lane = t & 63, quad = lane >> 4, l16 = lane & 15;
    const bf16x8v a0 = *(const bf16x8v*)(xT + (w * 16 + l16) * 72 + quad * 8);
    const bf16x8v a1 = *(const bf16x8v*)(xT + (w * 16 + l16) * 72 + 32 + quad * 8);

    floatx4 acc[4];
#pragma unroll
    for (int ot = 0; ot < 4; ++ot) {
        const float* wr = Wm + (ot * 16 + l16) * 64;
        float4 wa = *(const float4*)(wr + quad * 8);
        float4 wb = *(const float4*)(wr + quad * 8 + 4);
        float4 wc = *(const float4*)(wr + 32 + quad * 8);
        float4 wd = *(const float4*)(wr + 32 + quad * 8 + 4);
        bf16x8v b0, b1;
        b0[0]=(__bf16)wa.x; b0[1]=(__bf16)wa.y; b0[2]=(__bf16)wa.z; b0[3]=(__bf16)wa.w;
        b0[4]=(__bf16)wb.x; b0[5]=(__bf16)wb.y; b0[6]=(__bf16)wb.z; b0[7]=(__bf16)wb.w;
        b1[0]=(__bf16)wc.x; b1[1]=(__bf16)wc.y; b1[2]=(__bf16)wc.z; b1[3]=(__bf16)wc.w;
        b1[4]=(__bf16)wd.x; b1[5]=(__bf16)wd.y; b1[6]=(__bf16)wd.z; b1[7]=(__bf16)wd.w;
        acc[ot] = floatx4{0.f, 0.f, 0.f, 0.f};
        acc[ot] = __builtin_amdgcn_mfma_f32_16x16x32_bf16(a0, b0, acc[ot], 0, 0, 0);
        acc[ot] = __builtin_amdgcn_mfma_f32_16x16x32_bf16(a1, b1, acc[ot], 0, 0, 0);
    }
    __syncthreads();

#pragma unroll
    for (int ot = 0; ot < 4; ++ot) {
        const float bo = bias[ot * 16 + l16] * QKSCALE;
#pragma unroll
        for (int r = 0; r < 4; ++r)
            xT[(w * 16 + quad * 4 + r) * 72 + ot * 16 + l16] = (__bf16)(acc[ot][r] + bo);
    }
    __syncthreads();

    const int n = t >> 2, seg = t & 3;
    __bf16* dst = qkT + (size_t)(b * 4096 + n0 + n) * 64 + seg * 16;
    *(bf16x8v*)dst       = *(const bf16x8v*)(xT + n * 72 + seg * 16);
    *(bf16x8v*)(dst + 8) = *(const bf16x8v*)(xT + n * 72 + seg * 16 + 8);
}

// ---------------------------------------------------------------------------
// Kernel 2: flash-style attention. Block = (b, 128-q tile, m-chunk). 4 waves
// x 32 q. Double-buffered K/V LDS, ONE barrier per iter, reg-prefetch spanning
// compute. S^T = K·Q^T; p = exp2(sT) feeds PV directly as K=16 MFMA
// B-operands. V staging is a pure bf16 copy from xb (no cvt), stored with
// permuted columns j = quad*16 + mt*4 + (m&3).
// ---------------------------------------------------------------------------
#define BUFB 18432   // bytes per K+V buffer

template<int SPLIT, int ITERS>
__global__ __launch_bounds__(256, 4) void attn_kernel(const __bf16* __restrict__ xb,
                                                      const __bf16* __restrict__ qkT,
                                                      __bf16* __restrict__ Opart,
                                                      float* __restrict__ Lpart) {
    __shared__ __align__(16) char smem[36864];
    float* Olds = (float*)smem;                   // epilogue alias: [64 c][132 q]

    const int t   = threadIdx.x;
    const int blk = blockIdx.x;
    const int xcd = blk & 7;                      // XCD round-robin
    const int b   = xcd >> 1;                     // each b pinned to 2 XCDs
    const int sub = ((blk >> 3) << 1) | (xcd & 1);
    const int qt  = sub / SPLIT;
    const int s   = sub % SPLIT;
    const int n0  = qt << 7;
    const int pblk = (b * 32 + qt) * SPLIT + s;

    const int w = t >> 6, lane = t & 63, quad = lane >> 4, l16 = lane & 15;

    // Q B-frags: B[k=c][n=q], q = w*32 + qt2*16 + l16
    bf16x8v fq[2][2];
#pragma unroll
    for (int qt2 = 0; qt2 < 2; ++qt2) {
        const __bf16* qrow = qkT + (size_t)(b * 4096 + n0 + w * 32 + qt2 * 16 + l16) * 64;
        fq[qt2][0] = *(const bf16x8v*)(qrow + quad * 8);
        fq[qt2][1] = *(const bf16x8v*)(qrow + 32 + quad * 8);
    }

    floatx4 oacc[2][4];
#pragma unroll
    for (int i = 0; i < 2; ++i)
#pragma unroll
        for (int j = 0; j < 4; ++j) oacc[i][j] = floatx4{0.f, 0.f, 0.f, 0.f};
    float rs[2] = {0.f, 0.f};

    // staging address components (constant per thread)
    const int krow = t >> 3, kc8 = (t & 7) * 8;          // K: 2 chunks (rows +0,+32)
    const int vc   = t >> 3, vh  = t & 7;                // V: 2 chunks (rows +0,+32)
    const int vjlo = (((2 * vh) & 3) * 16) + (((2 * vh) >> 2) * 4);
    const int vjhi = (((2 * vh + 1) & 3) * 16) + (((2 * vh + 1) >> 2) * 4);
    const __bf16* kgp = qkT + (size_t)b * 4096 * 64 + (size_t)s * (64 * ITERS) * 64;
    const __bf16* vgp = xb + (size_t)b * 64 * 4096 + s * (64 * ITERS);

    // initial prefetch (iter 0)
    uint4 kpre[2];
    uint4 vpre[2];
#pragma unroll
    for (int i = 0; i < 2; ++i) {
        kpre[i] = *(const uint4*)(kgp + (size_t)(krow + i * 32) * 64 + kc8);
        vpre[i] = *(const uint4*)(vgp + (size_t)(vc + i * 32) * 4096 + vh * 8);
    }

    for (int it = 0; it < ITERS; ++it) {
        __bf16* Kb = (__bf16*)(smem + (it & 1) * BUFB);
        __bf16* Vb = (__bf16*)(smem + (it & 1) * BUFB + 9216);

        // ---- commit prefetched tile (regs loaded a full iter ago).
        // WAR vs compute(it-2) on this buffer is fenced by barrier(it-1).
#pragma unroll
        for (int i = 0; i < 2; ++i) {
            *(uint4*)(Kb + (krow + i * 32) * 72 + kc8) = kpre[i];
            uint2 lo = {vpre[i].x, vpre[i].y};
            uint2 hi = {vpre[i].z, vpre[i].w};
            *(uint2*)(Vb + (vc + i * 32) * 72 + vjlo) = lo;
            *(uint2*)(Vb + (vc + i * 32) * 72 + vjhi) = hi;
        }
        __syncthreads();   // the ONLY barrier per iter

        // ---- issue next tile's loads (latency spans entire compute phase)
        if (it + 1 < ITERS) {
            const int m1 = (it + 1) << 6;
#pragma unroll
            for (int i = 0; i < 2; ++i) {
                kpre[i] = *(const uint4*)(kgp + (size_t)(m1 + krow + i * 32) * 64 + kc8);
                vpre[i] = *(const uint4*)(vgp + (size_t)(vc + i * 32) * 4096 + m1 + vh * 8);
            }
        }

        // ---- S^T = K·Q^T: D row = m_local = quad*4+r, col = q = l16
        bf16x4v pf[4][2];
#pragma unroll
        for (int mt = 0; mt < 4; ++mt) {
            const __bf16* kr = Kb + (mt * 16 + l16) * 72;
            bf16x8v ak0 = *(const bf16x8v*)(kr + quad * 8);
            bf16x8v ak1 = *(const bf16x8v*)(kr + 32 + quad * 8);
#pragma unroll
            for (int qt2 = 0; qt2 < 2; ++qt2) {
                floatx4 sT = {0.f, 0.f, 0.f, 0.f};
                sT = __builtin_amdgcn_mfma_f32_16x16x32_bf16(ak0, fq[qt2][0], sT, 0, 0, 0);
                sT = __builtin_amdgcn_mfma_f32_16x16x32_bf16(ak1, fq[qt2][1], sT, 0, 0, 0);
                float p0 = exp2f(sT[0]), p1 = exp2f(sT[1]);   // scale pre-folded
                float p2 = exp2f(sT[2]), p3 = exp2f(sT[3]);
                rs[qt2] += (p0 + p1) + (p2 + p3);
                bf16x4v pv;
                pv[0] = (__bf16)p0; pv[1] = (__bf16)p1; pv[2] = (__bf16)p2; pv[3] = (__bf16)p3;
                pf[mt][qt2] = pv;
            }
        }

        // ---- O^T += V^T·P^T : A-frags for all 4 mt from 2 b128 per ct
#pragma unroll
        for (int ct = 0; ct < 4; ++ct) {
            const __bf16* vb = Vb + (ct * 16 + l16) * 72 + quad * 16;
            bf16x8v v01 = *(const bf16x8v*)vb;        // mt0 (elems 0-3), mt1 (4-7)
            bf16x8v v23 = *(const bf16x8v*)(vb + 8);  // mt2, mt3
            bf16x4v av0 = {v01[0], v01[1], v01[2], v01[3]};
            bf16x4v av1 = {v01[4], v01[5], v01[6], v01[7]};
            bf16x4v av2 = {v23[0], v23[1], v23[2], v23[3]};
            bf16x4v av3 = {v23[4], v23[5], v23[6], v23[7]};
#pragma unroll
            for (int qt2 = 0; qt2 < 2; ++qt2) {
                oacc[qt2][ct] = mfma16(av0, pf[0][qt2], oacc[qt2][ct]);
                oacc[qt2][ct] = mfma16(av1, pf[1][qt2], oacc[qt2][ct]);
                oacc[qt2][ct] = mfma16(av2, pf[2][qt2], oacc[qt2][ct]);
                oacc[qt2][ct] = mfma16(av3, pf[3][qt2], oacc[qt2][ct]);
            }
        }
    }

    // rowsum: lane holds partial for q=qt2*16+l16 over its quad's m-rows
#pragma unroll
    for (int qt2 = 0; qt2 < 2; ++qt2) {
        float v = rs[qt2];
        v += __shfl_xor(v, 16, 64);
        v += __shfl_xor(v, 32, 64);
        if (quad == 0)
            Lpart[(size_t)pblk * 128 + w * 32 + qt2 * 16 + l16] = v;
    }

    __syncthreads();   // all LDS tile reads done before aliasing as Olds

    // O^T D-layout: c = ct*16 + quad*4 + r, q = w*32 + qt2*16 + l16
#pragma unroll
    for (int qt2 = 0; qt2 < 2; ++qt2)
#pragma unroll
        for (int ct = 0; ct < 4; ++ct)
#pragma unroll
            for (int r = 0; r < 4; ++r)
                Olds[(ct * 16 + quad * 4 + r) * 132 + w * 32 + qt2 * 16 + l16] = oacc[qt2][ct][r];
    __syncthreads();

    // coalesced bf16 partial stores: Opart[pblk][c][q]
    const int c = t >> 2, seg = t & 3;
#pragma unroll
    for (int i = 0; i < 4; ++i) {
        floatx4 v0 = *(const floatx4*)(Olds + c * 132 + seg * 32 + i * 8);
        floatx4 v1 = *(const floatx4*)(Olds + c * 132 + seg * 32 + i * 8 + 4);
        bf16x8v pk;
        pk[0]=(__bf16)v0[0]; pk[1]=(__bf16)v0[1]; pk[2]=(__bf16)v0[2]; pk[3]=(__bf16)v0[3];
        pk[4]=(__bf16)v1[0]; pk[5]=(__bf16)v1[1]; pk[6]=(__bf16)v1[2]; pk[7]=(__bf16)v1[3];
        *(bf16x8v*)(Opart + (size_t)pblk * 8192 + c * 128 + seg * 32 + i * 8) = pk;
    }
}

// ---------------------------------------------------------------------------
// Kernel 3: combine SPLIT m-chunk partials, normalize, store fp32 output.
// ---------------------------------------------------------------------------
template<int SPLIT>
__global__ __launch_bounds__(256) void reduce_kernel(const __bf16* __restrict__ Opart,
                                                     const float* __restrict__ Lpart,
                                                     float* __restrict__ out) {
    __shared__ float linv[128];
    const int blk = blockIdx.x;           // bq*4 + cq
    const int bq = blk >> 2, cq = blk & 3;
    const int b = bq >> 5, qt = bq & 31;
    const int t = threadIdx.x;

    if (t < 128) {
        float sl = 0.f;
#pragma unroll
        for (int s = 0; s < SPLIT; ++s)
            sl += Lpart[((size_t)bq * SPLIT + s) * 128 + t];
        linv[t] = 1.0f / sl;
    }
    __syncthreads();

    const int c  = cq * 16 + (t >> 4);     // channel
    const int q8 = (t & 15) * 8;           // q offset (8 per thread)

    float a[8] = {0.f,0.f,0.f,0.f,0.f,0.f,0.f,0.f};
#pragma unroll
    for (int s = 0; s < SPLIT; ++s) {
        bf16x8v v = *(const bf16x8v*)(Opart + ((size_t)bq * SPLIT + s) * 8192 + c * 128 + q8);
#pragma unroll
        for (int k = 0; k < 8; ++k) a[k] += (float)v[k];
    }
    float* op = out + (size_t)(b * 64 + c) * 4096 + qt * 128 + q8;
    float4 o0, o1;
    o0.x = a[0]*linv[q8+0]; o0.y = a[1]*linv[q8+1]; o0.z = a[2]*linv[q8+2]; o0.w = a[3]*linv[q8+3];
    o1.x = a[4]*linv[q8+4]; o1.y = a[5]*linv[q8+5]; o1.z = a[6]*linv[q8+6]; o1.w = a[7]*linv[q8+7];
    *(float4*)op       = o0;
    *(float4*)(op + 4) = o1;
}

// ---------------------------------------------------------------------------
extern "C" void kernel_launch(void* const* d_in, const int* in_sizes, int n_in,
                              void* d_out, int out_size, void* d_ws, size_t ws_size,
                              hipStream_t stream) {
    const float* x    = (const float*)d_in[0];   // [4][64][4096]
    const float* Wm   = (const float*)d_in[1];   // [64][64]
    const float* bias = (const float*)d_in[2];   // [64]
    float* out = (float*)d_out;                  // [4][64][4096]

    char* ws = (char*)d_ws;
    __bf16* qkT = (__bf16*)ws;                   // 2 MB [4][4096][64] bf16 (pre-scaled)
    __bf16* xb  = (__bf16*)(ws + 2097152);       // 2 MB [4][64][4096] bf16 (V source)
    const size_t HDR = 4194304;

    qk_kernel<<<BATCH * (NSP / 64), 256, 0, stream>>>(x, Wm, bias, qkT, xb);

    const size_t needBig = HDR + (size_t)1024 * 8192 * 2 + (size_t)1024 * 128 * 4;  // ~21.5 MB
    if (ws_size >= needBig) {
        __bf16* Opart = (__bf16*)(ws + HDR);                          // 16 MB [1024][64][128]
        float*  Lpart = (float*)(ws + HDR + (size_t)1024 * 8192 * 2); // 512 KB
        attn_kernel<8, 8><<<BATCH * 32 * 8, 256, 0, stream>>>(xb, qkT, Opart, Lpart);
        reduce_kernel<8><<<512, 256, 0, stream>>>(Opart, Lpart, out);
    } else {
        __bf16* Opart = (__bf16*)(ws + HDR);                          // 8 MB [512][64][128]
        float*  Lpart = (float*)(ws + HDR + (size_t)512 * 8192 * 2);  // 256 KB
        attn_kernel<4, 16><<<BATCH * 32 * 4, 256, 0, stream>>>(xb, qkT, Opart, Lpart);
        reduce_kernel<4><<<512, 256, 0, stream>>>(Opart, Lpart, out);
    }
}